// Round 12
// baseline (79.839 us; speedup 1.0000x reference)
//
#include <hip/hip_runtime.h>
#include <math.h>

#define B_   2
#define S_   16384
#define SK_  1024
#define IMW_ 128
#define EPS_ 1e-5f

typedef __attribute__((ext_vector_type(8))) short short8v;
typedef __attribute__((ext_vector_type(4))) short short4v;
typedef __attribute__((ext_vector_type(4))) float f32x4;

__device__ __forceinline__ ushort f2bfu(float x) {
    uint u = __float_as_uint(x);
    u += 0x7fffu + ((u >> 16) & 1u);   // RNE
    return (ushort)(u >> 16);
}
__device__ __forceinline__ uint cvtpk(float a, float b) {  // [bf16(a) | bf16(b)<<16]
    uint r;
    asm("v_cvt_pk_bf16_f32 %0, %1, %2" : "=v"(r) : "v"(a), "v"(b));
    return r;
}
__device__ __forceinline__ short8v pack8(float4 a, float4 b) {
    union { uint4 u; short8v s; } c;
    c.u = make_uint4(cvtpk(a.x, a.y), cvtpk(a.z, a.w), cvtpk(b.x, b.y), cvtpk(b.z, b.w));
    return c.s;
}

// ---------------------------------------------------------------- prep
__global__ __launch_bounds__(256) void k_prep(
    const float* __restrict__ Wsr, const float* __restrict__ Wq,
    const float* __restrict__ Wk,  const float* __restrict__ Wv,
    const float* __restrict__ fc,
    ushort* __restrict__ Wsrb, ushort* __restrict__ Wqb,
    ushort* __restrict__ Wkb,  ushort* __restrict__ Wvb,
    float* __restrict__ frk, float* __restrict__ fik)
{
    const int blk = blockIdx.x, t = threadIdx.x;
    if (blk < 64) {                         // Wsr -> Wsrb[co][tap*128+ci]
        int i = blk * 256 + t;              // 16384
        int co = i >> 7, ci = i & 127;
        const float* src = Wsr + (size_t)i * 16;
        float4 v0 = *(const float4*)(src);
        float4 v1 = *(const float4*)(src + 4);
        float4 v2 = *(const float4*)(src + 8);
        float4 v3 = *(const float4*)(src + 12);
        float vv[16] = {v0.x, v0.y, v0.z, v0.w, v1.x, v1.y, v1.z, v1.w,
                        v2.x, v2.y, v2.z, v2.w, v3.x, v3.y, v3.z, v3.w};
        ushort* dst = Wsrb + (size_t)co * 2048 + ci;
        #pragma unroll
        for (int tap = 0; tap < 16; ++tap) dst[tap * 128] = f2bfu(vv[tap]);
    } else if (blk < 88) {                  // W casts
        int seg = (blk - 64) >> 3;          // 0=Wq 1=Wk 2=Wv
        const float* src = (seg == 0) ? Wq : (seg == 1) ? Wk : Wv;
        ushort* dst = (seg == 0) ? Wqb : (seg == 1) ? Wkb : Wvb;
        int i = ((blk - 64) & 7) * 2048 + t * 8;
        float4 a = *(const float4*)(src + i);
        float4 b = *(const float4*)(src + i + 4);
        *(uint4*)(dst + i) = make_uint4(cvtpk(a.x, a.y), cvtpk(a.z, a.w),
                                        cvtpk(b.x, b.y), cvtpk(b.z, b.w));
    } else {                                // freq 4x4 means
        int idx = (blk - 88) * 256 + t;     // 32768 = 1024 pos * 32 c
        int c = idx & 31, kk = idx >> 5;
        int y = kk >> 5, x = kk & 31;
        float sr = 0.f, si = 0.f;
        #pragma unroll
        for (int i1 = 0; i1 < 4; ++i1)
            #pragma unroll
            for (int i3 = 0; i3 < 4; ++i3) {
                int s = (4 * y + i1) * IMW_ + 4 * x + i3;
                sr += fc[s * 64 + 2 * c];
                si += fc[s * 64 + 2 * c + 1];
            }
        frk[idx] = sr * 0.0625f;
        fik[idx] = si * 0.0625f;
    }
}

// ---------------------------------------------------------------- fused conv + LN + K/V GEMM
// 512 blocks x 256 thr / 4 waves; block owns 4 patch rows (full K=2048, no split-K).
// Wave w: co slice 32w..32w+31 (2 mt). N=16 MFMA tile holds 4 real pos (cols duplicated).
__global__ __launch_bounds__(256) void k_cvkv(
    const float* __restrict__ hid, const ushort* __restrict__ Wsrb,
    const float* __restrict__ bsr, const float* __restrict__ lng,
    const float* __restrict__ lnb, const float* __restrict__ FRK,
    const float* __restrict__ FIK, const ushort* __restrict__ Wkb,
    const ushort* __restrict__ Wvb, const float* __restrict__ bk,
    const float* __restrict__ bv, ushort* __restrict__ Kb,
    ushort* __restrict__ VTb)
{
    __shared__ ushort sP[2][4][512];   // [buf][pos][k-chunk], 16B units XOR-swizzled (8 KB)
    __shared__ ushort sXb[4][128];     // LN'd X bf16, unit-swizzled (1 KB)
    __shared__ float  sRed[2][4][16];  // [sum|sumsq][wave][col]

    const int t = threadIdx.x;
    const int lane = t & 63, w = t >> 6;
    const int g = lane >> 4, ln = lane & 15;
    const int rowg = blockIdx.x * 4;          // global row in [0,2048)
    const int b = rowg >> 10;
    const int posB = rowg & 1023;             // pos-in-batch base

    const int sp = t >> 6;                    // staged pos 0..3
    const int su = t & 63;                    // 16B unit within row
    auto stage = [&](int c, int buf) {
        int tap = c * 4 + (su >> 4);
        int ci  = (su & 15) * 8;
        int pg  = posB + sp;
        int y = pg >> 5, x = pg & 31;
        const float* hp = hid + ((size_t)b * S_ + (4 * y + (tap >> 2)) * IMW_ + 4 * x + (tap & 3)) * 128 + ci;
        short8v v = pack8(*(const float4*)hp, *(const float4*)(hp + 4));
        *(short8v*)&sP[buf][sp][(su ^ (sp & 3)) * 8] = v;
    };

    // ---- conv: K = 2048 (tap-major), 4 chunks of 512, dbuf
    f32x4 acc[2];
    #pragma unroll
    for (int m = 0; m < 2; ++m)
        #pragma unroll
        for (int r = 0; r < 4; ++r) acc[m][r] = 0.f;

    stage(0, 0);
    __syncthreads();
    for (int c = 0; c < 4; ++c) {
        if (c < 3) stage(c + 1, (c + 1) & 1);
        const int bf = c & 1;
        #pragma unroll
        for (int ksl = 0; ksl < 16; ++ksl) {
            short8v xf = *(const short8v*)&sP[bf][ln & 3][(((4 * ksl + g) ^ (ln & 3))) * 8];
            int kg = c * 512 + ksl * 32 + 8 * g;
            #pragma unroll
            for (int m = 0; m < 2; ++m) {
                short8v wf = *(const short8v*)(Wsrb + (size_t)(32 * w + 16 * m + ln) * 2048 + kg);
                acc[m] = __builtin_amdgcn_mfma_f32_16x16x32_bf16(wf, xf, acc[m], 0, 0, 0);
            }
        }
        __syncthreads();
    }

    // ---- + b_sr, LN stats (E[x], E[x^2]); cross-wave reduce over 128 co
    float ps = 0.f, pq = 0.f;
    #pragma unroll
    for (int m = 0; m < 2; ++m) {
        float4 bs = *(const float4*)(bsr + 32 * w + 16 * m + 4 * g);
        #pragma unroll
        for (int r = 0; r < 4; ++r) {
            acc[m][r] += (&bs.x)[r];
            ps += acc[m][r];
            pq += acc[m][r] * acc[m][r];
        }
    }
    ps += __shfl_xor(ps, 16, 64); ps += __shfl_xor(ps, 32, 64);
    pq += __shfl_xor(pq, 16, 64); pq += __shfl_xor(pq, 32, 64);
    if (lane < 16) { sRed[0][w][ln] = ps; sRed[1][w][ln] = pq; }
    __syncthreads();
    float s4 = sRed[0][0][ln] + sRed[0][1][ln] + sRed[0][2][ln] + sRed[0][3][ln];
    float q4 = sRed[1][0][ln] + sRed[1][1][ln] + sRed[1][2][ln] + sRed[1][3][ln];
    float mu = s4 * (1.0f / 128.0f);
    float rstd = rsqrtf(fmaxf(q4 * (1.0f / 128.0f) - mu * mu, 0.f) + EPS_);

    // ---- normalize -> sXb (bf16, unit-swizzled); duplicate-lane writes are identical
    #pragma unroll
    for (int m = 0; m < 2; ++m) {
        int co0 = 32 * w + 16 * m + 4 * g;
        float4 gg = *(const float4*)(lng + co0);
        float4 bb = *(const float4*)(lnb + co0);
        float o0 = (acc[m][0] - mu) * rstd * gg.x + bb.x;
        float o1 = (acc[m][1] - mu) * rstd * gg.y + bb.y;
        float o2 = (acc[m][2] - mu) * rstd * gg.z + bb.z;
        float o3 = (acc[m][3] - mu) * rstd * gg.w + bb.w;
        int U = co0 >> 3, half = g & 1, p = ln & 3;
        *(uint2*)((char*)&sXb[0][0] + p * 256 + ((U ^ p) * 16) + half * 8) =
            make_uint2(cvtpk(o0, o1), cvtpk(o2, o3));
    }
    __syncthreads();

    // ---- K/V GEMM: waves 0,1 -> K (h=0,1); waves 2,3 -> V (h=0,1)
    short8v xn[4];
    #pragma unroll
    for (int ks = 0; ks < 4; ++ks)
        xn[ks] = *(const short8v*)((char*)&sXb[0][0] + (ln & 3) * 256 + (((4 * ks + g) ^ (ln & 3)) * 16));

    const int h = w & 1;
    const ushort* Wb = (w < 2) ? Wkb : Wvb;
    f32x4 acc2[4];
    #pragma unroll
    for (int mt = 0; mt < 4; ++mt)
        #pragma unroll
        for (int r = 0; r < 4; ++r) acc2[mt][r] = 0.f;
    #pragma unroll
    for (int mt = 0; mt < 4; ++mt)
        #pragma unroll
        for (int ks = 0; ks < 4; ++ks) {
            short8v wf = *(const short8v*)(Wb + (size_t)(64 * h + 16 * mt + ln) * 128 + 32 * ks + 8 * g);
            acc2[mt] = __builtin_amdgcn_mfma_f32_16x16x32_bf16(wf, xn[ks], acc2[mt], 0, 0, 0);
        }

    if (ln < 4) {
        const int posg = posB + ln;
        const int bh = b * 2 + h;
        if (w < 2) {       // K: bias + RoPE(freq means)
            #pragma unroll
            for (int mt = 0; mt < 4; ++mt) {
                int col0 = 16 * mt + 4 * g;
                float4 bkv = *(const float4*)(bk + 64 * h + col0);
                float a0 = acc2[mt][0] + bkv.x, a1 = acc2[mt][1] + bkv.y;
                float a2 = acc2[mt][2] + bkv.z, a3 = acc2[mt][3] + bkv.w;
                float2 frv = *(const float2*)(FRK + (size_t)posg * 32 + (col0 >> 1));
                float2 fiv = *(const float2*)(FIK + (size_t)posg * 32 + (col0 >> 1));
                float o0 = a0 * frv.x - a1 * fiv.x;
                float o1 = a0 * fiv.x + a1 * frv.x;
                float o2 = a2 * frv.y - a3 * fiv.y;
                float o3 = a2 * fiv.y + a3 * frv.y;
                *(uint2*)(Kb + ((size_t)bh * SK_ + posg) * 64 + col0) =
                    make_uint2(cvtpk(o0, o1), cvtpk(o2, o3));
            }
        } else {           // V: bias -> VTb[bh][d][pos]
            #pragma unroll
            for (int mt = 0; mt < 4; ++mt) {
                int col0 = 16 * mt + 4 * g;
                float4 bvv = *(const float4*)(bv + 64 * h + col0);
                #pragma unroll
                for (int r = 0; r < 4; ++r)
                    VTb[((size_t)bh * 64 + col0 + r) * SK_ + posg] =
                        f2bfu(acc2[mt][r] + (&bvv.x)[r]);
            }
        }
    }
}

// ---------------------------------------------------------------- flash attention (R9 verbatim)
// 512 blocks x 256 thr / 4 waves; wave owns 32 q rows x full 1024 kv.
// Fixed-max softmax. Double-buffered XOR-swizzled LDS (1 barrier/chunk);
// V stored kv-permuted so B-frags are single b128 reads. Loads issued 2 chunks ahead.
__global__ __launch_bounds__(256) void k_attn(
    const float* __restrict__ hid, const ushort* __restrict__ Wqb,
    const float* __restrict__ bq, const float* __restrict__ fc,
    const ushort* __restrict__ Kb, const ushort* __restrict__ VTb,
    float* __restrict__ out)
{
    __shared__ ushort sK[2][64][64];   // [buf][kv][d]    pitch 128B, XOR-swizzled
    __shared__ ushort sV[2][64][64];   // [buf][d][kvperm] pitch 128B, XOR-swizzled

    const int t = threadIdx.x;
    const int lane = t & 63, w = t >> 6;
    const int g = lane >> 4, ln = lane & 15;
    const int sbid = (blockIdx.x & 7) * 64 + (blockIdx.x >> 3);  // XCD swizzle (512%8==0)
    const int bh = sbid >> 7;
    const int q0b = (sbid & 127) * 128;
    const int b = bh >> 1, h = bh & 1;

    char* sQt = (char*)&sK[0][0][0];   // Q transit: 128 rows x 128B (= both K bufs)

    // ---- Q-GEMM: wave w owns q rows q0b + w*32 .. +31 (2 q-tiles) + RoPE -> transit
    {
        f32x4 qa[2][4];
        #pragma unroll
        for (int qt = 0; qt < 2; ++qt)
            #pragma unroll
            for (int mt = 0; mt < 4; ++mt)
                #pragma unroll
                for (int r = 0; r < 4; ++r) qa[qt][mt][r] = 0.f;

        #pragma unroll
        for (int ks = 0; ks < 4; ++ks) {
            short8v xf[2];
            #pragma unroll
            for (int qt = 0; qt < 2; ++qt) {
                const float* hp = hid + ((size_t)b * S_ + q0b + w * 32 + 16 * qt + ln) * 128 + 32 * ks + 8 * g;
                xf[qt] = pack8(*(const float4*)hp, *(const float4*)(hp + 4));
            }
            #pragma unroll
            for (int mt = 0; mt < 4; ++mt) {
                short8v wf = *(const short8v*)(Wqb + (size_t)(64 * h + 16 * mt + ln) * 128 + 32 * ks + 8 * g);
                qa[0][mt] = __builtin_amdgcn_mfma_f32_16x16x32_bf16(wf, xf[0], qa[0][mt], 0, 0, 0);
                qa[1][mt] = __builtin_amdgcn_mfma_f32_16x16x32_bf16(wf, xf[1], qa[1][mt], 0, 0, 0);
            }
        }
        const float scale = 0.18033688011112042f;   // 0.125 * log2(e)
        #pragma unroll
        for (int qt = 0; qt < 2; ++qt) {
            const int r = w * 32 + 16 * qt + ln;    // transit row
            const int pos = q0b + r;
            #pragma unroll
            for (int mt = 0; mt < 4; ++mt) {
                int col0 = 16 * mt + 4 * g;
                float4 fv = *(const float4*)(fc + (size_t)pos * 64 + col0);
                float4 bqv = *(const float4*)(bq + 64 * h + col0);
                float a0 = qa[qt][mt][0] + bqv.x, a1 = qa[qt][mt][1] + bqv.y;
                float a2 = qa[qt][mt][2] + bqv.z, a3 = qa[qt][mt][3] + bqv.w;
                float o0 = (a0 * fv.x - a1 * fv.y) * scale;
                float o1 = (a0 * fv.y + a1 * fv.x) * scale;
                float o2 = (a2 * fv.z - a3 * fv.w) * scale;
                float o3 = (a2 * fv.w + a3 * fv.z) * scale;
                int cb = ((col0 >> 3) ^ (r & 7));
                *(uint2*)(sQt + r * 128 + cb * 16 + (g & 1) * 8) =
                    make_uint2(cvtpk(o0, o1), cvtpk(o2, o3));
            }
        }
    }
    // reload own rows as B-frags (wave-private rows: no barrier needed)
    short8v qf[2][2];
    #pragma unroll
    for (int qt = 0; qt < 2; ++qt)
        #pragma unroll
        for (int ks = 0; ks < 2; ++ks) {
            const int r = w * 32 + 16 * qt + ln;
            qf[qt][ks] = *(const short8v*)(sQt + r * 128 + (((4 * ks + g) ^ (r & 7)) * 16));
        }
    __syncthreads();   // all transit reads done; staging may overwrite

    // ---- staging: 256 thr; thread covers f0=t, f1=t+256 (row = f>>3, m = f&7)
    const int r0 = t >> 3,        m0 = t & 7;
    const int r1 = (t + 256) >> 3, m1 = t & 7;        // (t+256)&7 == t&7
    const int vA0 = 32 * (m0 >> 2) + 4 * (m0 & 3);    // permuted V gather base
    const int vA1 = 32 * (m1 >> 2) + 4 * (m1 & 3);
    const ushort* kgB = Kb  + (size_t)bh * SK_ * 64;
    const ushort* vgB = VTb + (size_t)bh * 64 * SK_;

    uint4 kb0, kb1, vb0, vb1;
    auto loadCh = [&](int ch) {
        const ushort* kp = kgB + (size_t)ch * 4096;
        kb0 = *(const uint4*)(kp + r0 * 64 + m0 * 8);
        kb1 = *(const uint4*)(kp + r1 * 64 + m1 * 8);
        const ushort* vp = vgB + ch * 64;
        uint2 a0 = *(const uint2*)(vp + (size_t)r0 * SK_ + vA0);
        uint2 b0 = *(const uint2*)(vp + (size_t)r0 * SK_ + vA0 + 16);
        uint2 a1 = *(const uint2*)(vp + (size_t)r1 * SK_ + vA1);
        uint2 b1 = *(const uint2*)(vp + (size_t)r1 * SK_ + vA1 + 16);
        vb0 = make_uint4(a0.x, a0.y, b0.x, b0.y);
        vb1 = make_uint4(a1.x, a1.y, b1.x, b1.y);
    };
    auto writeBuf = [&](int p) {
        char* kd = (char*)&sK[p][0][0];
        char* vd = (char*)&sV[p][0][0];
        *(uint4*)(kd + r0 * 128 + ((m0 ^ (r0 & 7)) * 16)) = kb0;
        *(uint4*)(kd + r1 * 128 + ((m1 ^ (r1 & 7)) * 16)) = kb1;
        *(uint4*)(vd + r0 * 128 + ((m0 ^ (r0 & 7)) * 16)) = vb0;
        *(uint4*)(vd + r1 * 128 + ((m1 ^ (r1 & 7)) * 16)) = vb1;
    };

    f32x4 ctx[2][4];
    #pragma unroll
    for (int qt = 0; qt < 2; ++qt)
        #pragma unroll
        for (int dt = 0; dt < 4; ++dt)
            #pragma unroll
            for (int r = 0; r < 4; ++r) ctx[qt][dt][r] = 0.f;
    float l_run[2] = {0.f, 0.f};

    loadCh(0);
    writeBuf(0);
    loadCh(1);
    __syncthreads();

    for (int ch = 0; ch < 16; ++ch) {
        const int p = ch & 1;
        if (ch < 15) {             // stage next chunk into the other buffer
            writeBuf(p ^ 1);
            if (ch < 14) loadCh(ch + 2);
        }

        // QK^T (swapped): D rows = kv-local (4g+r), cols = q-local (ln)
        f32x4 sc[4][2];
        #pragma unroll
        for (int kvt = 0; kvt < 4; ++kvt)
            #pragma unroll
            for (int qt = 0; qt < 2; ++qt)
                #pragma unroll
                for (int r = 0; r < 4; ++r) sc[kvt][qt][r] = 0.f;
        #pragma unroll
        for (int ks = 0; ks < 2; ++ks)
            #pragma unroll
            for (int kvt = 0; kvt < 4; ++kvt) {
                const int r = 16 * kvt + ln;
                short8v kf = *(const short8v*)((const char*)&sK[p][0][0] +
                                               r * 128 + (((4 * ks + g) ^ (r & 7)) * 16));
                sc[kvt][0] = __builtin_amdgcn_mfma_f32_16x16x32_bf16(kf, qf[0][ks], sc[kvt][0], 0, 0, 0);
                sc[kvt][1] = __builtin_amdgcn_mfma_f32_16x16x32_bf16(kf, qf[1][ks], sc[kvt][1], 0, 0, 0);
            }

        // fixed-max softmax: P = exp2(s), lane-local l
        #pragma unroll
        for (int qt = 0; qt < 2; ++qt)
            #pragma unroll
            for (int kvt = 0; kvt < 4; ++kvt)
                #pragma unroll
                for (int r = 0; r < 4; ++r) {
                    float ev = __builtin_amdgcn_exp2f(sc[kvt][qt][r]);
                    sc[kvt][qt][r] = ev;
                    l_run[qt] += ev;
                }

        // PV: P packed in-register; V single b128 (kv-permuted layout matches P's k-map)
        #pragma unroll
        for (int ks2 = 0; ks2 < 2; ++ks2) {
            union { uint4 u; short8v s; } pf[2];
            #pragma unroll
            for (int qt = 0; qt < 2; ++qt) {
                pf[qt].u.x = cvtpk(sc[2 * ks2][qt][0],     sc[2 * ks2][qt][1]);
                pf[qt].u.y = cvtpk(sc[2 * ks2][qt][2],     sc[2 * ks2][qt][3]);
                pf[qt].u.z = cvtpk(sc[2 * ks2 + 1][qt][0], sc[2 * ks2 + 1][qt][1]);
                pf[qt].u.w = cvtpk(sc[2 * ks2 + 1][qt][2], sc[2 * ks2 + 1][qt][3]);
            }
            #pragma unroll
            for (int dt = 0; dt < 4; ++dt) {
                const int dd = 16 * dt + ln;
                short8v vf = *(const short8v*)((const char*)&sV[p][0][0] +
                                               dd * 128 + (((4 * ks2 + g) ^ (dd & 7)) * 16));
                ctx[0][dt] = __builtin_amdgcn_mfma_f32_16x16x32_bf16(pf[0].s, vf, ctx[0][dt], 0, 0, 0);
                ctx[1][dt] = __builtin_amdgcn_mfma_f32_16x16x32_bf16(pf[1].s, vf, ctx[1][dt], 0, 0, 0);
            }
        }

        __syncthreads();
    }

    // ---- single end reduction of l per q-tile, then write
    #pragma unroll
    for (int qt = 0; qt < 2; ++qt) {
        float l = l_run[qt];
        l += __shfl_xor(l, 16, 64);
        l += __shfl_xor(l, 32, 64);
        float inv = 1.0f / l;
        #pragma unroll
        for (int r = 0; r < 4; ++r) {
            float ir = __shfl(inv, 4 * g + r, 64);
            int q = q0b + w * 32 + 16 * qt + 4 * g + r;
            float* dst = out + ((size_t)b * S_ + q) * 128 + h * 64;
            #pragma unroll
            for (int dt = 0; dt < 4; ++dt)
                dst[16 * dt + ln] = ctx[qt][dt][r] * ir;
        }
    }
}

// ---------------------------------------------------------------- launch
extern "C" void kernel_launch(void* const* d_in, const int* in_sizes, int n_in,
                              void* d_out, int out_size, void* d_ws, size_t ws_size,
                              hipStream_t stream) {
    const float* hid = (const float*)d_in[0];
    const float* fc  = (const float*)d_in[1];
    const float* Wq  = (const float*)d_in[2];
    const float* bq  = (const float*)d_in[3];
    const float* Wk  = (const float*)d_in[4];
    const float* bk  = (const float*)d_in[5];
    const float* Wv  = (const float*)d_in[6];
    const float* bv  = (const float*)d_in[7];
    const float* Wsr = (const float*)d_in[8];
    const float* bsr = (const float*)d_in[9];
    const float* lng = (const float*)d_in[10];
    const float* lnb = (const float*)d_in[11];
    float* out = (float*)d_out;

    float* ws = (float*)d_ws;
    float*  FRK  = ws + 2097152;                 //    32,768
    float*  FIK  = ws + 2129920;                 //    32,768
    ushort* Wsrb = (ushort*)(ws + 2162688);      //   262,144 us
    ushort* Kb   = (ushort*)(ws + 2293760);      //   262,144 us
    ushort* VTb  = (ushort*)(ws + 2424832);      //   262,144 us
    ushort* Wqb  = (ushort*)(ws + 2555904);      //    16,384 us
    ushort* Wkb  = (ushort*)(ws + 2564096);      //    16,384 us
    ushort* Wvb  = (ushort*)(ws + 2572288);      //    16,384 us

    k_prep<<<216, 256, 0, stream>>>(Wsr, Wq, Wk, Wv, fc,
                                    Wsrb, Wqb, Wkb, Wvb, FRK, FIK);
    k_cvkv<<<512, 256, 0, stream>>>(hid, Wsrb, bsr, lng, lnb, FRK, FIK,
                                    Wkb, Wvb, bk, bv, Kb, VTb);
    k_attn<<<512, 256, 0, stream>>>(hid, Wqb, bq, fc, Kb, VTb, out);
}

// Round 13
// 77.411 us; speedup vs baseline: 1.0314x; 1.0314x over previous
//
#include <hip/hip_runtime.h>
#include <math.h>

#define B_   2
#define S_   16384
#define SK_  1024
#define IMW_ 128
#define EPS_ 1e-5f

typedef __attribute__((ext_vector_type(8))) short short8v;
typedef __attribute__((ext_vector_type(4))) short short4v;
typedef __attribute__((ext_vector_type(4))) float f32x4;

__device__ __forceinline__ ushort f2bfu(float x) {
    uint u = __float_as_uint(x);
    u += 0x7fffu + ((u >> 16) & 1u);   // RNE
    return (ushort)(u >> 16);
}
__device__ __forceinline__ uint cvtpk(float a, float b) {  // [bf16(a) | bf16(b)<<16]
    uint r;
    asm("v_cvt_pk_bf16_f32 %0, %1, %2" : "=v"(r) : "v"(a), "v"(b));
    return r;
}
__device__ __forceinline__ short8v pack8(float4 a, float4 b) {
    union { uint4 u; short8v s; } c;
    c.u = make_uint4(cvtpk(a.x, a.y), cvtpk(a.z, a.w), cvtpk(b.x, b.y), cvtpk(b.z, b.w));
    return c.s;
}

// ---------------------------------------------------------------- prep: Wsr -> Wsrb[co][tap*128+ci] bf16
__global__ __launch_bounds__(256) void k_prep(const float* __restrict__ Wsr,
                                              ushort* __restrict__ Wsrb) {
    int i = blockIdx.x * 256 + threadIdx.x;   // 64 blocks, 16384 (co,ci) pairs
    int co = i >> 7, ci = i & 127;
    const float* src = Wsr + (size_t)i * 16;
    float4 v0 = *(const float4*)(src);
    float4 v1 = *(const float4*)(src + 4);
    float4 v2 = *(const float4*)(src + 8);
    float4 v3 = *(const float4*)(src + 12);
    float vv[16] = {v0.x, v0.y, v0.z, v0.w, v1.x, v1.y, v1.z, v1.w,
                    v2.x, v2.y, v2.z, v2.w, v3.x, v3.y, v3.z, v3.w};
    ushort* dst = Wsrb + (size_t)co * 2048 + ci;
    #pragma unroll
    for (int tap = 0; tap < 16; ++tap) dst[tap * 128] = f2bfu(vv[tap]);
}

// ---------------------------------------------------------------- conv, split-K=8 (R9 verbatim)
__global__ __launch_bounds__(512) void k_conv(
    const float* __restrict__ hid, const ushort* __restrict__ Wsrb,
    float* __restrict__ partial)
{
    const int t = threadIdx.x;
    const int lane = t & 63, w = t >> 6;
    const int g = lane >> 4, ln = lane & 15;
    const int b = blockIdx.x >> 6, pt = blockIdx.x & 63;
    const int pos = pt * 16 + ln;
    const int y = pos >> 5, x = pos & 31;

    f32x4 acc[8];
    #pragma unroll
    for (int mt = 0; mt < 8; ++mt)
        #pragma unroll
        for (int r = 0; r < 4; ++r) acc[mt][r] = 0.f;

    #pragma unroll
    for (int st = 0; st < 8; ++st) {
        const int tap = 2 * w + (st >> 2);
        const int ci0 = (st & 3) * 32;
        const int ky = tap >> 2, kx = tap & 3;
        const float* hp = hid + ((size_t)b * S_ + (4 * y + ky) * IMW_ + 4 * x + kx) * 128 + ci0 + 8 * g;
        short8v xf = pack8(*(const float4*)hp, *(const float4*)(hp + 4));
        #pragma unroll
        for (int mt = 0; mt < 8; ++mt) {
            short8v wf = *(const short8v*)(Wsrb + (size_t)(16 * mt + ln) * 2048 + tap * 128 + ci0 + 8 * g);
            acc[mt] = __builtin_amdgcn_mfma_f32_16x16x32_bf16(wf, xf, acc[mt], 0, 0, 0);
        }
    }
    float* dst = partial + ((size_t)w * 2048 + b * 1024 + pos) * 128 + 4 * g;
    #pragma unroll
    for (int mt = 0; mt < 8; ++mt)
        *(float4*)(dst + 16 * mt) = make_float4(acc[mt][0], acc[mt][1], acc[mt][2], acc[mt][3]);
}

// ---------------------------------------------------------------- LN + K/V GEMM + RoPE
// R9 structure + inline freq-means (R4 pattern) + inline fp32 W pack (R4 pattern).
__global__ __launch_bounds__(256) void k_lnkv(
    const float* __restrict__ partial, const float* __restrict__ bsr,
    const float* __restrict__ lng, const float* __restrict__ lnb,
    const float* __restrict__ fc,
    const float* __restrict__ Wk, const float* __restrict__ Wv,
    const float* __restrict__ bk, const float* __restrict__ bv,
    ushort* __restrict__ Kb, ushort* __restrict__ VTb)
{
    __shared__ ushort sXb[16][128];
    __shared__ float  sFR[16][32];
    __shared__ float  sFI[16][32];
    const int t = threadIdx.x;
    const int lane = t & 63, w = t >> 6;
    const int g = lane >> 4, ln = lane & 15;
    const int b = blockIdx.x >> 6;
    const int row0 = blockIdx.x * 16;
    const int pos0 = (blockIdx.x & 63) * 16;

    // ---- freq 4x4 means for this block's 16 positions (R4 pattern)
    #pragma unroll
    for (int i = 0; i < 2; ++i) {
        int pid = t + 256 * i;                 // 512 = 16 pos * 32 c
        int p = pid >> 5, c = pid & 31;
        int pg = pos0 + p;
        int y = pg >> 5, x = pg & 31;
        float sr = 0.f, si = 0.f;
        #pragma unroll
        for (int i1 = 0; i1 < 4; ++i1)
            #pragma unroll
            for (int i3 = 0; i3 < 4; ++i3) {
                int s = (4 * y + i1) * IMW_ + 4 * x + i3;
                sr += fc[s * 64 + 2 * c];
                si += fc[s * 64 + 2 * c + 1];
            }
        sFR[p][c] = sr * 0.0625f;
        sFI[p][c] = si * 0.0625f;
    }

    {
        const int row = t >> 4, j0 = (t & 15) * 8;
        float4 b0 = *(const float4*)(bsr + j0);
        float4 b1 = *(const float4*)(bsr + j0 + 4);
        float v[8] = {b0.x, b0.y, b0.z, b0.w, b1.x, b1.y, b1.z, b1.w};
        #pragma unroll
        for (int s = 0; s < 8; ++s) {
            const float* pp = partial + ((size_t)s * 2048 + row0 + row) * 128 + j0;
            float4 a = *(const float4*)pp;
            float4 c = *(const float4*)(pp + 4);
            v[0] += a.x; v[1] += a.y; v[2] += a.z; v[3] += a.w;
            v[4] += c.x; v[5] += c.y; v[6] += c.z; v[7] += c.w;
        }
        float s = v[0] + v[1] + v[2] + v[3] + v[4] + v[5] + v[6] + v[7];
        #pragma unroll
        for (int m = 1; m < 16; m <<= 1) s += __shfl_xor(s, m, 64);
        float mu = s * (1.0f / 128.0f);
        float d[8], vs = 0.f;
        #pragma unroll
        for (int j = 0; j < 8; ++j) { d[j] = v[j] - mu; vs += d[j] * d[j]; }
        #pragma unroll
        for (int m = 1; m < 16; m <<= 1) vs += __shfl_xor(vs, m, 64);
        float rstd = rsqrtf(vs * (1.0f / 128.0f) + EPS_);
        float4 g0 = *(const float4*)(lng + j0);
        float4 g1 = *(const float4*)(lng + j0 + 4);
        float4 c0 = *(const float4*)(lnb + j0);
        float4 c1 = *(const float4*)(lnb + j0 + 4);
        float o[8];
        o[0] = d[0] * rstd * g0.x + c0.x; o[1] = d[1] * rstd * g0.y + c0.y;
        o[2] = d[2] * rstd * g0.z + c0.z; o[3] = d[3] * rstd * g0.w + c0.w;
        o[4] = d[4] * rstd * g1.x + c1.x; o[5] = d[5] * rstd * g1.y + c1.y;
        o[6] = d[6] * rstd * g1.z + c1.z; o[7] = d[7] * rstd * g1.w + c1.w;
        *(uint4*)&sXb[row][j0 ^ ((row & 7) << 3)] =
            make_uint4(cvtpk(o[0], o[1]), cvtpk(o[2], o[3]),
                       cvtpk(o[4], o[5]), cvtpk(o[6], o[7]));
    }
    __syncthreads();

    short8v xn[4];
    #pragma unroll
    for (int ks = 0; ks < 4; ++ks)
        xn[ks] = *(const short8v*)&sXb[ln][(32 * ks + 8 * g) ^ ((ln & 7) << 3)];

    const int h = w & 1;
    const float* W = (w < 2) ? Wk : Wv;
    f32x4 acc2[4];
    #pragma unroll
    for (int mt = 0; mt < 4; ++mt)
        #pragma unroll
        for (int r = 0; r < 4; ++r) acc2[mt][r] = 0.f;
    #pragma unroll
    for (int mt = 0; mt < 4; ++mt)
        #pragma unroll
        for (int ks = 0; ks < 4; ++ks) {
            const float* wp = W + (size_t)(64 * h + 16 * mt + ln) * 128 + 32 * ks + 8 * g;
            short8v wf = pack8(*(const float4*)wp, *(const float4*)(wp + 4));
            acc2[mt] = __builtin_amdgcn_mfma_f32_16x16x32_bf16(wf, xn[ks], acc2[mt], 0, 0, 0);
        }

    const int posg = pos0 + ln;
    const int bh = b * 2 + h;
    if (w < 2) {
        #pragma unroll
        for (int mt = 0; mt < 4; ++mt) {
            int col0 = 16 * mt + 4 * g;
            float4 bkv = *(const float4*)(bk + 64 * h + col0);
            float a0 = acc2[mt][0] + bkv.x, a1 = acc2[mt][1] + bkv.y;
            float a2 = acc2[mt][2] + bkv.z, a3 = acc2[mt][3] + bkv.w;
            float2 frv = *(const float2*)&sFR[ln][col0 >> 1];
            float2 fiv = *(const float2*)&sFI[ln][col0 >> 1];
            float o0 = a0 * frv.x - a1 * fiv.x;
            float o1 = a0 * fiv.x + a1 * frv.x;
            float o2 = a2 * frv.y - a3 * fiv.y;
            float o3 = a2 * fiv.y + a3 * frv.y;
            *(uint2*)(Kb + ((size_t)bh * SK_ + posg) * 64 + col0) =
                make_uint2(cvtpk(o0, o1), cvtpk(o2, o3));
        }
    } else {
        #pragma unroll
        for (int mt = 0; mt < 4; ++mt) {
            int col0 = 16 * mt + 4 * g;
            float4 bvv = *(const float4*)(bv + 64 * h + col0);
            #pragma unroll
            for (int r = 0; r < 4; ++r)
                VTb[((size_t)bh * 64 + col0 + r) * SK_ + posg] =
                    f2bfu(acc2[mt][r] + (&bvv.x)[r]);
        }
    }
}

// ---------------------------------------------------------------- flash attention (R9 + setprio, Wq fp32)
// 512 blocks x 256 thr / 4 waves; wave owns 32 q rows x full 1024 kv.
// Fixed-max softmax. Double-buffered XOR-swizzled LDS (1 barrier/chunk);
// V stored kv-permuted so B-frags are single b128 reads. Loads issued 2 chunks ahead.
__global__ __launch_bounds__(256) void k_attn(
    const float* __restrict__ hid, const float* __restrict__ Wq,
    const float* __restrict__ bq, const float* __restrict__ fc,
    const ushort* __restrict__ Kb, const ushort* __restrict__ VTb,
    float* __restrict__ out)
{
    __shared__ ushort sK[2][64][64];   // [buf][kv][d]     128B pitch, XOR-swizzled
    __shared__ ushort sV[2][64][64];   // [buf][d][kvperm] 128B pitch, XOR-swizzled

    const int t = threadIdx.x;
    const int lane = t & 63, w = t >> 6;
    const int g = lane >> 4, ln = lane & 15;
    const int sbid = (blockIdx.x & 7) * 64 + (blockIdx.x >> 3);  // XCD swizzle (512%8==0)
    const int bh = sbid >> 7;
    const int q0b = (sbid & 127) * 128;
    const int b = bh >> 1, h = bh & 1;

    char* sQt = (char*)&sK[0][0][0];   // Q transit: 128 rows x 128B (= both K bufs)

    // ---- Q-GEMM: wave w owns q rows q0b + w*32 .. +31 (2 q-tiles) + RoPE -> transit
    {
        f32x4 qa[2][4];
        #pragma unroll
        for (int qt = 0; qt < 2; ++qt)
            #pragma unroll
            for (int mt = 0; mt < 4; ++mt)
                #pragma unroll
                for (int r = 0; r < 4; ++r) qa[qt][mt][r] = 0.f;

        #pragma unroll
        for (int ks = 0; ks < 4; ++ks) {
            short8v xf[2];
            #pragma unroll
            for (int qt = 0; qt < 2; ++qt) {
                const float* hp = hid + ((size_t)b * S_ + q0b + w * 32 + 16 * qt + ln) * 128 + 32 * ks + 8 * g;
                xf[qt] = pack8(*(const float4*)hp, *(const float4*)(hp + 4));
            }
            #pragma unroll
            for (int mt = 0; mt < 4; ++mt) {
                const float* wp = Wq + (size_t)(64 * h + 16 * mt + ln) * 128 + 32 * ks + 8 * g;
                short8v wf = pack8(*(const float4*)wp, *(const float4*)(wp + 4));
                qa[0][mt] = __builtin_amdgcn_mfma_f32_16x16x32_bf16(wf, xf[0], qa[0][mt], 0, 0, 0);
                qa[1][mt] = __builtin_amdgcn_mfma_f32_16x16x32_bf16(wf, xf[1], qa[1][mt], 0, 0, 0);
            }
        }
        const float scale = 0.18033688011112042f;   // 0.125 * log2(e)
        #pragma unroll
        for (int qt = 0; qt < 2; ++qt) {
            const int r = w * 32 + 16 * qt + ln;    // transit row
            const int pos = q0b + r;
            #pragma unroll
            for (int mt = 0; mt < 4; ++mt) {
                int col0 = 16 * mt + 4 * g;
                float4 fv = *(const float4*)(fc + (size_t)pos * 64 + col0);
                float4 bqv = *(const float4*)(bq + 64 * h + col0);
                float a0 = qa[qt][mt][0] + bqv.x, a1 = qa[qt][mt][1] + bqv.y;
                float a2 = qa[qt][mt][2] + bqv.z, a3 = qa[qt][mt][3] + bqv.w;
                float o0 = (a0 * fv.x - a1 * fv.y) * scale;
                float o1 = (a0 * fv.y + a1 * fv.x) * scale;
                float o2 = (a2 * fv.z - a3 * fv.w) * scale;
                float o3 = (a2 * fv.w + a3 * fv.z) * scale;
                int cb = ((col0 >> 3) ^ (r & 7));
                *(uint2*)(sQt + r * 128 + cb * 16 + (g & 1) * 8) =
                    make_uint2(cvtpk(o0, o1), cvtpk(o2, o3));
            }
        }
    }
    // reload own rows as B-frags (wave-private rows: no barrier needed)
    short8v qf[2][2];
    #pragma unroll
    for (int qt = 0; qt < 2; ++qt)
        #pragma unroll
        for (int ks = 0; ks < 2; ++ks) {
            const int r = w * 32 + 16 * qt + ln;
            qf[qt][ks] = *(const short8v*)(sQt + r * 128 + (((4 * ks + g) ^ (r & 7)) * 16));
        }
    __syncthreads();   // all transit reads done; staging may overwrite

    // ---- staging: 256 thr; thread covers f0=t, f1=t+256 (row = f>>3, m = f&7)
    const int r0 = t >> 3,        m0 = t & 7;
    const int r1 = (t + 256) >> 3, m1 = t & 7;        // (t+256)&7 == t&7
    const int vA0 = 32 * (m0 >> 2) + 4 * (m0 & 3);    // permuted V gather base
    const int vA1 = 32 * (m1 >> 2) + 4 * (m1 & 3);
    const ushort* kgB = Kb  + (size_t)bh * SK_ * 64;
    const ushort* vgB = VTb + (size_t)bh * 64 * SK_;

    uint4 kb0, kb1, vb0, vb1;
    auto loadCh = [&](int ch) {
        const ushort* kp = kgB + (size_t)ch * 4096;
        kb0 = *(const uint4*)(kp + r0 * 64 + m0 * 8);
        kb1 = *(const uint4*)(kp + r1 * 64 + m1 * 8);
        const ushort* vp = vgB + ch * 64;
        uint2 a0 = *(const uint2*)(vp + (size_t)r0 * SK_ + vA0);
        uint2 b0 = *(const uint2*)(vp + (size_t)r0 * SK_ + vA0 + 16);
        uint2 a1 = *(const uint2*)(vp + (size_t)r1 * SK_ + vA1);
        uint2 b1 = *(const uint2*)(vp + (size_t)r1 * SK_ + vA1 + 16);
        vb0 = make_uint4(a0.x, a0.y, b0.x, b0.y);
        vb1 = make_uint4(a1.x, a1.y, b1.x, b1.y);
    };
    auto writeBuf = [&](int p) {
        char* kd = (char*)&sK[p][0][0];
        char* vd = (char*)&sV[p][0][0];
        *(uint4*)(kd + r0 * 128 + ((m0 ^ (r0 & 7)) * 16)) = kb0;
        *(uint4*)(kd + r1 * 128 + ((m1 ^ (r1 & 7)) * 16)) = kb1;
        *(uint4*)(vd + r0 * 128 + ((m0 ^ (r0 & 7)) * 16)) = vb0;
        *(uint4*)(vd + r1 * 128 + ((m1 ^ (r1 & 7)) * 16)) = vb1;
    };

    f32x4 ctx[2][4];
    #pragma unroll
    for (int qt = 0; qt < 2; ++qt)
        #pragma unroll
        for (int dt = 0; dt < 4; ++dt)
            #pragma unroll
            for (int r = 0; r < 4; ++r) ctx[qt][dt][r] = 0.f;
    float l_run[2] = {0.f, 0.f};

    loadCh(0);
    writeBuf(0);
    loadCh(1);
    __syncthreads();

    for (int ch = 0; ch < 16; ++ch) {
        const int p = ch & 1;
        if (ch < 15) {             // stage next chunk into the other buffer
            writeBuf(p ^ 1);
            if (ch < 14) loadCh(ch + 2);
        }

        // QK^T (swapped): D rows = kv-local (4g+r), cols = q-local (ln)
        f32x4 sc[4][2];
        #pragma unroll
        for (int kvt = 0; kvt < 4; ++kvt)
            #pragma unroll
            for (int qt = 0; qt < 2; ++qt)
                #pragma unroll
                for (int r = 0; r < 4; ++r) sc[kvt][qt][r] = 0.f;
        __builtin_amdgcn_s_setprio(1);
        #pragma unroll
        for (int ks = 0; ks < 2; ++ks)
            #pragma unroll
            for (int kvt = 0; kvt < 4; ++kvt) {
                const int r = 16 * kvt + ln;
                short8v kf = *(const short8v*)((const char*)&sK[p][0][0] +
                                               r * 128 + (((4 * ks + g) ^ (r & 7)) * 16));
                sc[kvt][0] = __builtin_amdgcn_mfma_f32_16x16x32_bf16(kf, qf[0][ks], sc[kvt][0], 0, 0, 0);
                sc[kvt][1] = __builtin_amdgcn_mfma_f32_16x16x32_bf16(kf, qf[1][ks], sc[kvt][1], 0, 0, 0);
            }
        __builtin_amdgcn_s_setprio(0);

        // fixed-max softmax: P = exp2(s), lane-local l
        #pragma unroll
        for (int qt = 0; qt < 2; ++qt)
            #pragma unroll
            for (int kvt = 0; kvt < 4; ++kvt)
                #pragma unroll
                for (int r = 0; r < 4; ++r) {
                    float ev = __builtin_amdgcn_exp2f(sc[kvt][qt][r]);
                    sc[kvt][qt][r] = ev;
                    l_run[qt] += ev;
                }

        // PV: P packed in-register; V single b128 (kv-permuted layout matches P's k-map)
        #pragma unroll
        for (int ks2 = 0; ks2 < 2; ++ks2) {
            union { uint4 u; short8v s; } pf[2];
            #pragma unroll
            for (int qt = 0; qt < 2; ++qt) {
                pf[qt].u.x = cvtpk(sc[2 * ks2][qt][0],     sc[2 * ks2][qt][1]);
                pf[qt].u.y = cvtpk(sc[2 * ks2][qt][2],     sc[2 * ks2][qt][3]);
                pf[qt].u.z = cvtpk(sc[2 * ks2 + 1][qt][0], sc[2 * ks2 + 1][qt][1]);
                pf[qt].u.w = cvtpk(sc[2 * ks2 + 1][qt][2], sc[2 * ks2 + 1][qt][3]);
            }
            __builtin_amdgcn_s_setprio(1);
            #pragma unroll
            for (int dt = 0; dt < 4; ++dt) {
                const int dd = 16 * dt + ln;
                short8v vf = *(const short8v*)((const char*)&sV[p][0][0] +
                                               dd * 128 + (((4 * ks2 + g) ^ (dd & 7)) * 16));
                ctx[0][dt] = __builtin_amdgcn_mfma_f32_16x16x32_bf16(pf[0].s, vf, ctx[0][dt], 0, 0, 0);
                ctx[1][dt] = __builtin_amdgcn_mfma_f32_16x16x32_bf16(pf[1].s, vf, ctx[1][dt], 0, 0, 0);
            }
            __builtin_amdgcn_s_setprio(0);
        }

        __syncthreads();
    }

    // ---- single end reduction of l per q-tile, then write
    #pragma unroll
    for (int qt = 0; qt < 2; ++qt) {
        float l = l_run[qt];
        l += __shfl_xor(l, 16, 64);
        l += __shfl_xor(l, 32, 64);
        float inv = 1.0f / l;
        #pragma unroll
        for (int r = 0; r < 4; ++r) {
            float ir = __shfl(inv, 4 * g + r, 64);
            int q = q0b + w * 32 + 16 * qt + 4 * g + r;
            float* dst = out + ((size_t)b * S_ + q) * 128 + h * 64;
            #pragma unroll
            for (int dt = 0; dt < 4; ++dt)
                dst[16 * dt + ln] = ctx[qt][dt][r] * ir;
        }
    }
}

// ---------------------------------------------------------------- launch
extern "C" void kernel_launch(void* const* d_in, const int* in_sizes, int n_in,
                              void* d_out, int out_size, void* d_ws, size_t ws_size,
                              hipStream_t stream) {
    const float* hid = (const float*)d_in[0];
    const float* fc  = (const float*)d_in[1];
    const float* Wq  = (const float*)d_in[2];
    const float* bq  = (const float*)d_in[3];
    const float* Wk  = (const float*)d_in[4];
    const float* bk  = (const float*)d_in[5];
    const float* Wv  = (const float*)d_in[6];
    const float* bv  = (const float*)d_in[7];
    const float* Wsr = (const float*)d_in[8];
    const float* bsr = (const float*)d_in[9];
    const float* lng = (const float*)d_in[10];
    const float* lnb = (const float*)d_in[11];
    float* out = (float*)d_out;

    float* ws = (float*)d_ws;
    float*  partial = ws;                        // 2,097,152 fl (8 MB)
    ushort* Wsrb = (ushort*)(ws + 2097152);      //   262,144 us
    ushort* Kb   = (ushort*)(ws + 2228224);      //   262,144 us
    ushort* VTb  = (ushort*)(ws + 2359296);      //   262,144 us

    k_prep<<<64, 256, 0, stream>>>(Wsr, Wsrb);
    k_conv<<<128, 512, 0, stream>>>(hid, Wsrb, partial);
    k_lnkv<<<128, 256, 0, stream>>>(partial, bsr, lng, lnb, fc,
                                    Wk, Wv, bk, bv, Kb, VTb);
    k_attn<<<512, 256, 0, stream>>>(hid, Wq, bq, fc, Kb, VTb, out);
}

// Round 15
// 71.911 us; speedup vs baseline: 1.1102x; 1.0765x over previous
//
#include <hip/hip_runtime.h>
#include <math.h>

#define B_   2
#define S_   16384
#define SK_  1024
#define IMW_ 128
#define EPS_ 1e-5f

typedef __attribute__((ext_vector_type(8))) short short8v;
typedef __attribute__((ext_vector_type(4))) short short4v;
typedef __attribute__((ext_vector_type(4))) float f32x4;

__device__ __forceinline__ ushort f2bfu(float x) {
    uint u = __float_as_uint(x);
    u += 0x7fffu + ((u >> 16) & 1u);   // RNE
    return (ushort)(u >> 16);
}
__device__ __forceinline__ uint cvtpk(float a, float b) {  // [bf16(a) | bf16(b)<<16]
    uint r;
    asm("v_cvt_pk_bf16_f32 %0, %1, %2" : "=v"(r) : "v"(a), "v"(b));
    return r;
}
__device__ __forceinline__ short8v pack8(float4 a, float4 b) {
    union { uint4 u; short8v s; } c;
    c.u = make_uint4(cvtpk(a.x, a.y), cvtpk(a.z, a.w), cvtpk(b.x, b.y), cvtpk(b.z, b.w));
    return c.s;
}

// ---------------------------------------------------------------- prep
__global__ __launch_bounds__(256) void k_prep(
    const float* __restrict__ Wsr, const float* __restrict__ Wq,
    const float* __restrict__ Wk,  const float* __restrict__ Wv,
    const float* __restrict__ fc,
    ushort* __restrict__ Wsrb, ushort* __restrict__ Wqb,
    ushort* __restrict__ Wkb,  ushort* __restrict__ Wvb,
    float* __restrict__ frk, float* __restrict__ fik)
{
    const int blk = blockIdx.x, t = threadIdx.x;
    if (blk < 64) {                         // Wsr -> Wsrb[co][tap*128+ci]
        int i = blk * 256 + t;              // 16384
        int co = i >> 7, ci = i & 127;
        const float* src = Wsr + (size_t)i * 16;
        float4 v0 = *(const float4*)(src);
        float4 v1 = *(const float4*)(src + 4);
        float4 v2 = *(const float4*)(src + 8);
        float4 v3 = *(const float4*)(src + 12);
        float vv[16] = {v0.x, v0.y, v0.z, v0.w, v1.x, v1.y, v1.z, v1.w,
                        v2.x, v2.y, v2.z, v2.w, v3.x, v3.y, v3.z, v3.w};
        ushort* dst = Wsrb + (size_t)co * 2048 + ci;
        #pragma unroll
        for (int tap = 0; tap < 16; ++tap) dst[tap * 128] = f2bfu(vv[tap]);
    } else if (blk < 88) {                  // W casts
        int seg = (blk - 64) >> 3;          // 0=Wq 1=Wk 2=Wv
        const float* src = (seg == 0) ? Wq : (seg == 1) ? Wk : Wv;
        ushort* dst = (seg == 0) ? Wqb : (seg == 1) ? Wkb : Wvb;
        int i = ((blk - 64) & 7) * 2048 + t * 8;
        float4 a = *(const float4*)(src + i);
        float4 b = *(const float4*)(src + i + 4);
        *(uint4*)(dst + i) = make_uint4(cvtpk(a.x, a.y), cvtpk(a.z, a.w),
                                        cvtpk(b.x, b.y), cvtpk(b.z, b.w));
    } else {                                // freq 4x4 means
        int idx = (blk - 88) * 256 + t;     // 32768 = 1024 pos * 32 c
        int c = idx & 31, kk = idx >> 5;
        int y = kk >> 5, x = kk & 31;
        float sr = 0.f, si = 0.f;
        #pragma unroll
        for (int i1 = 0; i1 < 4; ++i1)
            #pragma unroll
            for (int i3 = 0; i3 < 4; ++i3) {
                int s = (4 * y + i1) * IMW_ + 4 * x + i3;
                sr += fc[s * 64 + 2 * c];
                si += fc[s * 64 + 2 * c + 1];
            }
        frk[idx] = sr * 0.0625f;
        fik[idx] = si * 0.0625f;
    }
}

// ---------------------------------------------------------------- conv, split-K=8
__global__ __launch_bounds__(512) void k_conv(
    const float* __restrict__ hid, const ushort* __restrict__ Wsrb,
    float* __restrict__ partial)
{
    const int t = threadIdx.x;
    const int lane = t & 63, w = t >> 6;
    const int g = lane >> 4, ln = lane & 15;
    const int b = blockIdx.x >> 6, pt = blockIdx.x & 63;
    const int pos = pt * 16 + ln;
    const int y = pos >> 5, x = pos & 31;

    f32x4 acc[8];
    #pragma unroll
    for (int mt = 0; mt < 8; ++mt)
        #pragma unroll
        for (int r = 0; r < 4; ++r) acc[mt][r] = 0.f;

    #pragma unroll
    for (int st = 0; st < 8; ++st) {
        const int tap = 2 * w + (st >> 2);
        const int ci0 = (st & 3) * 32;
        const int ky = tap >> 2, kx = tap & 3;
        const float* hp = hid + ((size_t)b * S_ + (4 * y + ky) * IMW_ + 4 * x + kx) * 128 + ci0 + 8 * g;
        short8v xf = pack8(*(const float4*)hp, *(const float4*)(hp + 4));
        #pragma unroll
        for (int mt = 0; mt < 8; ++mt) {
            short8v wf = *(const short8v*)(Wsrb + (size_t)(16 * mt + ln) * 2048 + tap * 128 + ci0 + 8 * g);
            acc[mt] = __builtin_amdgcn_mfma_f32_16x16x32_bf16(wf, xf, acc[mt], 0, 0, 0);
        }
    }
    float* dst = partial + ((size_t)w * 2048 + b * 1024 + pos) * 128 + 4 * g;
    #pragma unroll
    for (int mt = 0; mt < 8; ++mt)
        *(float4*)(dst + 16 * mt) = make_float4(acc[mt][0], acc[mt][1], acc[mt][2], acc[mt][3]);
}

// ---------------------------------------------------------------- LN + K/V GEMM + RoPE
__global__ __launch_bounds__(256) void k_lnkv(
    const float* __restrict__ partial, const float* __restrict__ bsr,
    const float* __restrict__ lng, const float* __restrict__ lnb,
    const float* __restrict__ FRK, const float* __restrict__ FIK,
    const ushort* __restrict__ Wkb, const ushort* __restrict__ Wvb,
    const float* __restrict__ bk, const float* __restrict__ bv,
    ushort* __restrict__ Kb, ushort* __restrict__ VTb)
{
    __shared__ ushort sXb[16][128];
    const int t = threadIdx.x;
    const int lane = t & 63, w = t >> 6;
    const int g = lane >> 4, ln = lane & 15;
    const int b = blockIdx.x >> 6;
    const int row0 = blockIdx.x * 16;
    const int pos0 = (blockIdx.x & 63) * 16;

    {
        const int row = t >> 4, j0 = (t & 15) * 8;
        float4 b0 = *(const float4*)(bsr + j0);
        float4 b1 = *(const float4*)(bsr + j0 + 4);
        float v[8] = {b0.x, b0.y, b0.z, b0.w, b1.x, b1.y, b1.z, b1.w};
        #pragma unroll
        for (int s = 0; s < 8; ++s) {
            const float* pp = partial + ((size_t)s * 2048 + row0 + row) * 128 + j0;
            float4 a = *(const float4*)pp;
            float4 c = *(const float4*)(pp + 4);
            v[0] += a.x; v[1] += a.y; v[2] += a.z; v[3] += a.w;
            v[4] += c.x; v[5] += c.y; v[6] += c.z; v[7] += c.w;
        }
        float s = v[0] + v[1] + v[2] + v[3] + v[4] + v[5] + v[6] + v[7];
        #pragma unroll
        for (int m = 1; m < 16; m <<= 1) s += __shfl_xor(s, m, 64);
        float mu = s * (1.0f / 128.0f);
        float d[8], vs = 0.f;
        #pragma unroll
        for (int j = 0; j < 8; ++j) { d[j] = v[j] - mu; vs += d[j] * d[j]; }
        #pragma unroll
        for (int m = 1; m < 16; m <<= 1) vs += __shfl_xor(vs, m, 64);
        float rstd = rsqrtf(vs * (1.0f / 128.0f) + EPS_);
        float4 g0 = *(const float4*)(lng + j0);
        float4 g1 = *(const float4*)(lng + j0 + 4);
        float4 c0 = *(const float4*)(lnb + j0);
        float4 c1 = *(const float4*)(lnb + j0 + 4);
        float o[8];
        o[0] = d[0] * rstd * g0.x + c0.x; o[1] = d[1] * rstd * g0.y + c0.y;
        o[2] = d[2] * rstd * g0.z + c0.z; o[3] = d[3] * rstd * g0.w + c0.w;
        o[4] = d[4] * rstd * g1.x + c1.x; o[5] = d[5] * rstd * g1.y + c1.y;
        o[6] = d[6] * rstd * g1.z + c1.z; o[7] = d[7] * rstd * g1.w + c1.w;
        *(uint4*)&sXb[row][j0 ^ ((row & 7) << 3)] =
            make_uint4(cvtpk(o[0], o[1]), cvtpk(o[2], o[3]),
                       cvtpk(o[4], o[5]), cvtpk(o[6], o[7]));
    }
    __syncthreads();

    short8v xn[4];
    #pragma unroll
    for (int ks = 0; ks < 4; ++ks)
        xn[ks] = *(const short8v*)&sXb[ln][(32 * ks + 8 * g) ^ ((ln & 7) << 3)];

    const int h = w & 1;
    const ushort* Wb = (w < 2) ? Wkb : Wvb;
    f32x4 acc2[4];
    #pragma unroll
    for (int mt = 0; mt < 4; ++mt)
        #pragma unroll
        for (int r = 0; r < 4; ++r) acc2[mt][r] = 0.f;
    #pragma unroll
    for (int mt = 0; mt < 4; ++mt)
        #pragma unroll
        for (int ks = 0; ks < 4; ++ks) {
            short8v wf = *(const short8v*)(Wb + (size_t)(64 * h + 16 * mt + ln) * 128 + 32 * ks + 8 * g);
            acc2[mt] = __builtin_amdgcn_mfma_f32_16x16x32_bf16(wf, xn[ks], acc2[mt], 0, 0, 0);
        }

    const int posg = pos0 + ln;
    const int bh = b * 2 + h;
    if (w < 2) {
        #pragma unroll
        for (int mt = 0; mt < 4; ++mt) {
            int col0 = 16 * mt + 4 * g;
            float4 bkv = *(const float4*)(bk + 64 * h + col0);
            float a0 = acc2[mt][0] + bkv.x, a1 = acc2[mt][1] + bkv.y;
            float a2 = acc2[mt][2] + bkv.z, a3 = acc2[mt][3] + bkv.w;
            float2 frv = *(const float2*)(FRK + (size_t)posg * 32 + (col0 >> 1));
            float2 fiv = *(const float2*)(FIK + (size_t)posg * 32 + (col0 >> 1));
            float o0 = a0 * frv.x - a1 * fiv.x;
            float o1 = a0 * fiv.x + a1 * frv.x;
            float o2 = a2 * frv.y - a3 * fiv.y;
            float o3 = a2 * fiv.y + a3 * frv.y;
            *(uint2*)(Kb + ((size_t)bh * SK_ + posg) * 64 + col0) =
                make_uint2(cvtpk(o0, o1), cvtpk(o2, o3));
        }
    } else {
        #pragma unroll
        for (int mt = 0; mt < 4; ++mt) {
            int col0 = 16 * mt + 4 * g;
            float4 bvv = *(const float4*)(bv + 64 * h + col0);
            #pragma unroll
            for (int r = 0; r < 4; ++r)
                VTb[((size_t)bh * 64 + col0 + r) * SK_ + posg] =
                    f2bfu(acc2[mt][r] + (&bvv.x)[r]);
        }
    }
}

// ---------------------------------------------------------------- flash attention
// 512 blocks x 256 thr / 4 waves; wave owns 32 q rows x full 1024 kv.
// Fixed-max softmax. Double-buffered XOR-swizzled LDS (1 barrier/chunk);
// V stored kv-permuted so B-frags are single b128 reads. Loads issued 2 chunks ahead.
__global__ __launch_bounds__(256) void k_attn(
    const float* __restrict__ hid, const ushort* __restrict__ Wqb,
    const float* __restrict__ bq, const float* __restrict__ fc,
    const ushort* __restrict__ Kb, const ushort* __restrict__ VTb,
    float* __restrict__ out)
{
    __shared__ ushort sK[2][64][64];   // [buf][kv][d]    pitch 128B, XOR-swizzled
    __shared__ ushort sV[2][64][64];   // [buf][d][kvperm] pitch 128B, XOR-swizzled

    const int t = threadIdx.x;
    const int lane = t & 63, w = t >> 6;
    const int g = lane >> 4, ln = lane & 15;
    const int sbid = (blockIdx.x & 7) * 64 + (blockIdx.x >> 3);  // XCD swizzle (512%8==0)
    const int bh = sbid >> 7;
    const int q0b = (sbid & 127) * 128;
    const int b = bh >> 1, h = bh & 1;

    char* sQt = (char*)&sK[0][0][0];   // Q transit: 128 rows x 128B (= both K bufs)

    // ---- Q-GEMM: wave w owns q rows q0b + w*32 .. +31 (2 q-tiles) + RoPE -> transit
    {
        f32x4 qa[2][4];
        #pragma unroll
        for (int qt = 0; qt < 2; ++qt)
            #pragma unroll
            for (int mt = 0; mt < 4; ++mt)
                #pragma unroll
                for (int r = 0; r < 4; ++r) qa[qt][mt][r] = 0.f;

        #pragma unroll
        for (int ks = 0; ks < 4; ++ks) {
            short8v xf[2];
            #pragma unroll
            for (int qt = 0; qt < 2; ++qt) {
                const float* hp = hid + ((size_t)b * S_ + q0b + w * 32 + 16 * qt + ln) * 128 + 32 * ks + 8 * g;
                xf[qt] = pack8(*(const float4*)hp, *(const float4*)(hp + 4));
            }
            #pragma unroll
            for (int mt = 0; mt < 4; ++mt) {
                short8v wf = *(const short8v*)(Wqb + (size_t)(64 * h + 16 * mt + ln) * 128 + 32 * ks + 8 * g);
                qa[0][mt] = __builtin_amdgcn_mfma_f32_16x16x32_bf16(wf, xf[0], qa[0][mt], 0, 0, 0);
                qa[1][mt] = __builtin_amdgcn_mfma_f32_16x16x32_bf16(wf, xf[1], qa[1][mt], 0, 0, 0);
            }
        }
        const float scale = 0.18033688011112042f;   // 0.125 * log2(e)
        #pragma unroll
        for (int qt = 0; qt < 2; ++qt) {
            const int r = w * 32 + 16 * qt + ln;    // transit row
            const int pos = q0b + r;
            #pragma unroll
            for (int mt = 0; mt < 4; ++mt) {
                int col0 = 16 * mt + 4 * g;
                float4 fv = *(const float4*)(fc + (size_t)pos * 64 + col0);
                float4 bqv = *(const float4*)(bq + 64 * h + col0);
                float a0 = qa[qt][mt][0] + bqv.x, a1 = qa[qt][mt][1] + bqv.y;
                float a2 = qa[qt][mt][2] + bqv.z, a3 = qa[qt][mt][3] + bqv.w;
                float o0 = (a0 * fv.x - a1 * fv.y) * scale;
                float o1 = (a0 * fv.y + a1 * fv.x) * scale;
                float o2 = (a2 * fv.z - a3 * fv.w) * scale;
                float o3 = (a2 * fv.w + a3 * fv.z) * scale;
                int cb = ((col0 >> 3) ^ (r & 7));
                *(uint2*)(sQt + r * 128 + cb * 16 + (g & 1) * 8) =
                    make_uint2(cvtpk(o0, o1), cvtpk(o2, o3));
            }
        }
    }
    // reload own rows as B-frags (wave-private rows: no barrier needed)
    short8v qf[2][2];
    #pragma unroll
    for (int qt = 0; qt < 2; ++qt)
        #pragma unroll
        for (int ks = 0; ks < 2; ++ks) {
            const int r = w * 32 + 16 * qt + ln;
            qf[qt][ks] = *(const short8v*)(sQt + r * 128 + (((4 * ks + g) ^ (r & 7)) * 16));
        }
    __syncthreads();   // all transit reads done; staging may overwrite

    // ---- staging: 256 thr; thread covers f0=t, f1=t+256 (row = f>>3, m = f&7)
    const int r0 = t >> 3,        m0 = t & 7;
    const int r1 = (t + 256) >> 3, m1 = t & 7;        // (t+256)&7 == t&7
    const int vA0 = 32 * (m0 >> 2) + 4 * (m0 & 3);    // permuted V gather base
    const int vA1 = 32 * (m1 >> 2) + 4 * (m1 & 3);
    const ushort* kgB = Kb  + (size_t)bh * SK_ * 64;
    const ushort* vgB = VTb + (size_t)bh * 64 * SK_;

    uint4 kb0, kb1, vb0, vb1;
    auto loadCh = [&](int ch) {
        const ushort* kp = kgB + (size_t)ch * 4096;
        kb0 = *(const uint4*)(kp + r0 * 64 + m0 * 8);
        kb1 = *(const uint4*)(kp + r1 * 64 + m1 * 8);
        const ushort* vp = vgB + ch * 64;
        uint2 a0 = *(const uint2*)(vp + (size_t)r0 * SK_ + vA0);
        uint2 b0 = *(const uint2*)(vp + (size_t)r0 * SK_ + vA0 + 16);
        uint2 a1 = *(const uint2*)(vp + (size_t)r1 * SK_ + vA1);
        uint2 b1 = *(const uint2*)(vp + (size_t)r1 * SK_ + vA1 + 16);
        vb0 = make_uint4(a0.x, a0.y, b0.x, b0.y);
        vb1 = make_uint4(a1.x, a1.y, b1.x, b1.y);
    };
    auto writeBuf = [&](int p) {
        char* kd = (char*)&sK[p][0][0];
        char* vd = (char*)&sV[p][0][0];
        *(uint4*)(kd + r0 * 128 + ((m0 ^ (r0 & 7)) * 16)) = kb0;
        *(uint4*)(kd + r1 * 128 + ((m1 ^ (r1 & 7)) * 16)) = kb1;
        *(uint4*)(vd + r0 * 128 + ((m0 ^ (r0 & 7)) * 16)) = vb0;
        *(uint4*)(vd + r1 * 128 + ((m1 ^ (r1 & 7)) * 16)) = vb1;
    };

    f32x4 ctx[2][4];
    #pragma unroll
    for (int qt = 0; qt < 2; ++qt)
        #pragma unroll
        for (int dt = 0; dt < 4; ++dt)
            #pragma unroll
            for (int r = 0; r < 4; ++r) ctx[qt][dt][r] = 0.f;
    float l_run[2] = {0.f, 0.f};

    loadCh(0);
    writeBuf(0);
    loadCh(1);
    __syncthreads();

    for (int ch = 0; ch < 16; ++ch) {
        const int p = ch & 1;
        if (ch < 15) {             // stage next chunk into the other buffer
            writeBuf(p ^ 1);
            if (ch < 14) loadCh(ch + 2);
        }

        // QK^T (swapped): D rows = kv-local (4g+r), cols = q-local (ln)
        f32x4 sc[4][2];
        #pragma unroll
        for (int kvt = 0; kvt < 4; ++kvt)
            #pragma unroll
            for (int qt = 0; qt < 2; ++qt)
                #pragma unroll
                for (int r = 0; r < 4; ++r) sc[kvt][qt][r] = 0.f;
        #pragma unroll
        for (int ks = 0; ks < 2; ++ks)
            #pragma unroll
            for (int kvt = 0; kvt < 4; ++kvt) {
                const int r = 16 * kvt + ln;
                short8v kf = *(const short8v*)((const char*)&sK[p][0][0] +
                                               r * 128 + (((4 * ks + g) ^ (r & 7)) * 16));
                sc[kvt][0] = __builtin_amdgcn_mfma_f32_16x16x32_bf16(kf, qf[0][ks], sc[kvt][0], 0, 0, 0);
                sc[kvt][1] = __builtin_amdgcn_mfma_f32_16x16x32_bf16(kf, qf[1][ks], sc[kvt][1], 0, 0, 0);
            }

        // fixed-max softmax: P = exp2(s), lane-local l
        #pragma unroll
        for (int qt = 0; qt < 2; ++qt)
            #pragma unroll
            for (int kvt = 0; kvt < 4; ++kvt)
                #pragma unroll
                for (int r = 0; r < 4; ++r) {
                    float ev = __builtin_amdgcn_exp2f(sc[kvt][qt][r]);
                    sc[kvt][qt][r] = ev;
                    l_run[qt] += ev;
                }

        // PV: P packed in-register; V single b128 (kv-permuted layout matches P's k-map)
        #pragma unroll
        for (int ks2 = 0; ks2 < 2; ++ks2) {
            union { uint4 u; short8v s; } pf[2];
            #pragma unroll
            for (int qt = 0; qt < 2; ++qt) {
                pf[qt].u.x = cvtpk(sc[2 * ks2][qt][0],     sc[2 * ks2][qt][1]);
                pf[qt].u.y = cvtpk(sc[2 * ks2][qt][2],     sc[2 * ks2][qt][3]);
                pf[qt].u.z = cvtpk(sc[2 * ks2 + 1][qt][0], sc[2 * ks2 + 1][qt][1]);
                pf[qt].u.w = cvtpk(sc[2 * ks2 + 1][qt][2], sc[2 * ks2 + 1][qt][3]);
            }
            #pragma unroll
            for (int dt = 0; dt < 4; ++dt) {
                const int dd = 16 * dt + ln;
                short8v vf = *(const short8v*)((const char*)&sV[p][0][0] +
                                               dd * 128 + (((4 * ks2 + g) ^ (dd & 7)) * 16));
                ctx[0][dt] = __builtin_amdgcn_mfma_f32_16x16x32_bf16(pf[0].s, vf, ctx[0][dt], 0, 0, 0);
                ctx[1][dt] = __builtin_amdgcn_mfma_f32_16x16x32_bf16(pf[1].s, vf, ctx[1][dt], 0, 0, 0);
            }
        }

        __syncthreads();
    }

    // ---- single end reduction of l per q-tile, then write
    #pragma unroll
    for (int qt = 0; qt < 2; ++qt) {
        float l = l_run[qt];
        l += __shfl_xor(l, 16, 64);
        l += __shfl_xor(l, 32, 64);
        float inv = 1.0f / l;
        #pragma unroll
        for (int r = 0; r < 4; ++r) {
            float ir = __shfl(inv, 4 * g + r, 64);
            int q = q0b + w * 32 + 16 * qt + 4 * g + r;
            float* dst = out + ((size_t)b * S_ + q) * 128 + h * 64;
            #pragma unroll
            for (int dt = 0; dt < 4; ++dt)
                dst[16 * dt + ln] = ctx[qt][dt][r] * ir;
        }
    }
}

// ---------------------------------------------------------------- launch
extern "C" void kernel_launch(void* const* d_in, const int* in_sizes, int n_in,
                              void* d_out, int out_size, void* d_ws, size_t ws_size,
                              hipStream_t stream) {
    const float* hid = (const float*)d_in[0];
    const float* fc  = (const float*)d_in[1];
    const float* Wq  = (const float*)d_in[2];
    const float* bq  = (const float*)d_in[3];
    const float* Wk  = (const float*)d_in[4];
    const float* bk  = (const float*)d_in[5];
    const float* Wv  = (const float*)d_in[6];
    const float* bv  = (const float*)d_in[7];
    const float* Wsr = (const float*)d_in[8];
    const float* bsr = (const float*)d_in[9];
    const float* lng = (const float*)d_in[10];
    const float* lnb = (const float*)d_in[11];
    float* out = (float*)d_out;

    float* ws = (float*)d_ws;
    float*  partial = ws;                        // 2,097,152 fl (8 MB)
    float*  FRK  = ws + 2097152;                 //    32,768
    float*  FIK  = ws + 2129920;                 //    32,768
    ushort* Wsrb = (ushort*)(ws + 2162688);      //   262,144 us
    ushort* Kb   = (ushort*)(ws + 2293760);      //   262,144 us
    ushort* VTb  = (ushort*)(ws + 2424832);      //   262,144 us
    ushort* Wqb  = (ushort*)(ws + 2555904);      //    16,384 us
    ushort* Wkb  = (ushort*)(ws + 2564096);      //    16,384 us
    ushort* Wvb  = (ushort*)(ws + 2572288);      //    16,384 us

    k_prep<<<216, 256, 0, stream>>>(Wsr, Wq, Wk, Wv, fc,
                                    Wsrb, Wqb, Wkb, Wvb, FRK, FIK);
    k_conv<<<128, 512, 0, stream>>>(hid, Wsrb, partial);
    k_lnkv<<<128, 256, 0, stream>>>(partial, bsr, lng, lnb, FRK, FIK,
                                    Wkb, Wvb, bk, bv, Kb, VTb);
    k_attn<<<512, 256, 0, stream>>>(hid, Wqb, bq, fc, Kb, VTb, out);
}